// Round 2
// baseline (602.748 us; speedup 1.0000x reference)
//
#include <hip/hip_runtime.h>

// RGCN bipartite, FP32 in/out (reference dtype). Strategy:
//   agg-then-GEMM (GraphConv is linear), CSR built once, reused both layers.
//   GEMM = MFMA bf16 3-term split (hi/lo) => fp32-accurate on matrix pipe.
// Workspace use ~128 MB (P/H feature buffers fp32).

#define NA 50000
#define NB 10000
#define NE 300000
#define FDIM 256

typedef unsigned short u16;
typedef unsigned int u32;
typedef __attribute__((ext_vector_type(8))) short short8;
typedef __attribute__((ext_vector_type(4))) float f32x4;

__device__ __forceinline__ float bf2f(u16 h){
  union { u32 u; float f; } x; x.u = ((u32)h) << 16; return x.f;
}
__device__ __forceinline__ u16 f2bf(float f){
  union { float f; u32 u; } x; x.f = f;
  u32 r = (x.u + 0x7FFFu + ((x.u >> 16) & 1u)) >> 16;   // RNE
  return (u16)r;
}

// ---------- zero int scratch ----------
__global__ void zero_ints(int* __restrict__ a, int na, int* __restrict__ b, int nb){
  int g = blockIdx.x * blockDim.x + threadIdx.x;
  int s = gridDim.x * blockDim.x;
  for (int i = g; i < na; i += s) a[i] = 0;
  for (int i = g; i < nb; i += s) b[i] = 0;
}

// ---------- degree histograms ----------
__global__ void hist_kernel(const int* __restrict__ bs, const int* __restrict__ bd,
                            const int* __restrict__ isc, const int* __restrict__ idt,
                            int* __restrict__ c_bs, int* __restrict__ c_bd,
                            int* __restrict__ c_is, int* __restrict__ c_id){
  int g = blockIdx.x * blockDim.x + threadIdx.x;
  int s = gridDim.x * blockDim.x;
  for (int e = g; e < NE; e += s){
    atomicAdd(&c_bs[bs[e]], 1);
    atomicAdd(&c_bd[bd[e]], 1);
    atomicAdd(&c_is[isc[e]], 1);
    atomicAdd(&c_id[idt[e]], 1);
  }
}

// ---------- exclusive scan: block 0 -> bel offsets (NB), block 1 -> inc (NA) ----
__global__ __launch_bounds__(1024) void scan_kernel(const int* __restrict__ c_bd,
                                                    const int* __restrict__ c_id,
                                                    int* __restrict__ off_bel,
                                                    int* __restrict__ off_inc){
  const int* cnt; int* off; int n;
  if (blockIdx.x == 0){ cnt = c_bd; off = off_bel; n = NB; }
  else                { cnt = c_id; off = off_inc; n = NA; }
  __shared__ int wsum[16];
  __shared__ int carry, chunkTot;
  int tid = threadIdx.x, lane = tid & 63, wid = tid >> 6;
  if (tid == 0) carry = 0;
  __syncthreads();
  for (int base = 0; base < n; base += 4096){
    int i0 = base + tid * 4;
    int v[4];
#pragma unroll
    for (int r = 0; r < 4; ++r){ int idx = i0 + r; v[r] = (idx < n) ? cnt[idx] : 0; }
    int s = v[0] + v[1] + v[2] + v[3];
    int x = s;
#pragma unroll
    for (int d = 1; d < 64; d <<= 1){ int t = __shfl_up(x, d, 64); if (lane >= d) x += t; }
    if (lane == 63) wsum[wid] = x;
    __syncthreads();
    if (wid == 0){
      int ws = (lane < 16) ? wsum[lane] : 0;
#pragma unroll
      for (int d = 1; d < 16; d <<= 1){ int t = __shfl_up(ws, d, 64); if (lane >= d) ws += t; }
      if (lane < 16) wsum[lane] = ws;
      if (lane == 15) chunkTot = ws;
    }
    __syncthreads();
    int waveBase = (wid == 0) ? 0 : wsum[wid - 1];
    int run = carry + waveBase + (x - s);
#pragma unroll
    for (int r = 0; r < 4; ++r){ int idx = i0 + r; if (idx < n) off[idx] = run; run += v[r]; }
    __syncthreads();
    if (tid == 0) carry += chunkTot;
    __syncthreads();
  }
  if (tid == 0) off[n] = carry;
}

// ---------- rsqrt(max(deg,1)) scales ----------
__global__ void scales_kernel(const int* __restrict__ c_bs, const int* __restrict__ c_bd,
                              const int* __restrict__ c_is, const int* __restrict__ c_id,
                              float* __restrict__ s_ob, float* __restrict__ s_ib,
                              float* __restrict__ s_oi, float* __restrict__ s_ii){
  int g = blockIdx.x * blockDim.x + threadIdx.x;
  int s = gridDim.x * blockDim.x;
  for (int i = g; i < NA; i += s){
    int a = c_bs[i]; s_ob[i] = rsqrtf((float)(a > 1 ? a : 1));
    int b = c_id[i]; s_ii[i] = rsqrtf((float)(b > 1 ? b : 1));
    if (i < NB){
      int c = c_bd[i]; s_ib[i] = rsqrtf((float)(c > 1 ? c : 1));
      int d = c_is[i]; s_oi[i] = rsqrtf((float)(d > 1 ? d : 1));
    }
  }
}

// ---------- CSR fill ----------
__global__ void fill_kernel(const int* __restrict__ bs, const int* __restrict__ bd,
                            const int* __restrict__ isc, const int* __restrict__ idt,
                            const int* __restrict__ off_bel, const int* __restrict__ off_inc,
                            int* __restrict__ cur_bel, int* __restrict__ cur_inc,
                            int* __restrict__ csr_bel, int* __restrict__ csr_inc){
  int g = blockIdx.x * blockDim.x + threadIdx.x;
  int s = gridDim.x * blockDim.x;
  for (int e = g; e < NE; e += s){
    int d0 = bd[e];
    int p0 = off_bel[d0] + atomicAdd(&cur_bel[d0], 1);
    csr_bel[p0] = bs[e];
    int d1 = idt[e];
    int p1 = off_inc[d1] + atomicAdd(&cur_inc[d1], 1);
    csr_inc[p1] = isc[e];
  }
}

// ---------- pack fp32 W into MFMA B-fragment order, hi/lo bf16 split ----------
// B frag (16x16x32): lane holds B[k=(lane>>4)*8+j][n=lane&15], j=0..7
// layout per matrix: tile = kt*nT+nt, elem index = tile*512 + lane*8 + j
__global__ void pack_kernel(const float* __restrict__ W1b, const float* __restrict__ W1i,
                            const float* __restrict__ W2b, const float* __restrict__ W2i,
                            u16* __restrict__ pwh, u16* __restrict__ pwl){
  int g = blockIdx.x * blockDim.x + threadIdx.x;
  int s = gridDim.x * blockDim.x;
  const int total = 65536 + 65536 + 32768 + 32768;
  for (int t = g; t < total; t += s){
    const float* W; int N; int tt;
    if (t < 65536)       { W = W1b; N = 256; tt = t; }
    else if (t < 131072) { W = W1i; N = 256; tt = t - 65536; }
    else if (t < 163840) { W = W2b; N = 128; tt = t - 131072; }
    else                 { W = W2i; N = 128; tt = t - 163840; }
    int j = tt & 7, lane = (tt >> 3) & 63, tile = tt >> 9;
    int nT = N >> 4;
    int nt = tile % nT, kt = tile / nT;
    int k = kt * 32 + ((lane >> 4) << 3) + j;
    int n = nt * 16 + (lane & 15);
    float v = W[k * N + n];
    u16 hi = f2bf(v);
    float r = v - bf2f(hi);
    pwh[t] = hi;
    pwl[t] = f2bf(r);
  }
}

// ---------- aggregation (fp32): P[dst] = sum_{e->dst} X[src]*ss[src] ----------
// one wave per dst row; lane owns 4 of the 256 columns (float4)
__global__ __launch_bounds__(256) void agg_kernel(const float* __restrict__ X,
                                                  const float* __restrict__ ss,
                                                  const int* __restrict__ off,
                                                  const int* __restrict__ csr,
                                                  float* __restrict__ P, int nDst){
  int wave = blockIdx.x * (blockDim.x >> 6) + (threadIdx.x >> 6);
  int lane = threadIdx.x & 63;
  if (wave >= nDst) return;
  int b0 = off[wave], b1 = off[wave + 1];
  int c = lane * 4;
  float a0 = 0.f, a1 = 0.f, a2 = 0.f, a3 = 0.f;
  int j = b0;
  for (; j + 1 < b1; j += 2){
    int s0 = csr[j], s1 = csr[j + 1];
    float sc0 = ss[s0], sc1 = ss[s1];
    float4 v0 = *(const float4*)(X + (size_t)s0 * FDIM + c);
    float4 v1 = *(const float4*)(X + (size_t)s1 * FDIM + c);
    a0 += v0.x * sc0; a1 += v0.y * sc0; a2 += v0.z * sc0; a3 += v0.w * sc0;
    a0 += v1.x * sc1; a1 += v1.y * sc1; a2 += v1.z * sc1; a3 += v1.w * sc1;
  }
  if (j < b1){
    int s0 = csr[j];
    float sc0 = ss[s0];
    float4 v0 = *(const float4*)(X + (size_t)s0 * FDIM + c);
    a0 += v0.x * sc0; a1 += v0.y * sc0; a2 += v0.z * sc0; a3 += v0.w * sc0;
  }
  float4 o; o.x = a0; o.y = a1; o.z = a2; o.w = a3;
  *(float4*)(P + (size_t)wave * FDIM + c) = o;
}

// ---------- GEMM: C[M,N] = relu?( (A[M,256] @ W) * rs[m] + bias[n] ) ----------
// fp32 via 3-term bf16 split MFMA: Ah*Wh + Al*Wh + Ah*Wl
// A frag: lane holds A[m=lane&15][k=(lane>>4)*8+j]; C/D: row=(lane>>4)*4+r, col=lane&15
__global__ __launch_bounds__(256) void gemm_kernel(const float* __restrict__ A,
                                                   const u16* __restrict__ PWH,
                                                   const u16* __restrict__ PWL,
                                                   const float* __restrict__ bias,
                                                   const float* __restrict__ rs,
                                                   float* __restrict__ C,
                                                   int M, int N, int doRelu){
  int wave = blockIdx.x * (blockDim.x >> 6) + (threadIdx.x >> 6);
  int lane = threadIdx.x & 63;
  int strips = M >> 4;
  if (wave >= strips) return;
  int m0 = wave << 4;
  int r16 = lane & 15, quad = lane >> 4;
  const float* aBase = A + (size_t)(m0 + r16) * 256 + quad * 8;
  short8 ah[8], al[8];
#pragma unroll
  for (int kt = 0; kt < 8; ++kt){
    float4 p0 = *(const float4*)(aBase + kt * 32);
    float4 p1 = *(const float4*)(aBase + kt * 32 + 4);
    float v[8] = {p0.x, p0.y, p0.z, p0.w, p1.x, p1.y, p1.z, p1.w};
    short8 h, l;
#pragma unroll
    for (int j = 0; j < 8; ++j){
      u16 hb = f2bf(v[j]);
      float r = v[j] - bf2f(hb);
      h[j] = (short)hb;
      l[j] = (short)f2bf(r);
    }
    ah[kt] = h; al[kt] = l;
  }
  float rscale[4];
#pragma unroll
  for (int r = 0; r < 4; ++r) rscale[r] = rs[m0 + quad * 4 + r];
  int nT = N >> 4;
  for (int nt = 0; nt < nT; ++nt){
    f32x4 acc = {0.f, 0.f, 0.f, 0.f};
    const u16* bh = PWH + ((size_t)nt * 64 + lane) * 8;
    const u16* bl = PWL + ((size_t)nt * 64 + lane) * 8;
#pragma unroll
    for (int kt = 0; kt < 8; ++kt){
      short8 wh = *(const short8*)(bh + (size_t)kt * nT * 512);
      short8 wl = *(const short8*)(bl + (size_t)kt * nT * 512);
      acc = __builtin_amdgcn_mfma_f32_16x16x32_bf16(ah[kt], wh, acc, 0, 0, 0);
      acc = __builtin_amdgcn_mfma_f32_16x16x32_bf16(al[kt], wh, acc, 0, 0, 0);
      acc = __builtin_amdgcn_mfma_f32_16x16x32_bf16(ah[kt], wl, acc, 0, 0, 0);
    }
    int col = nt * 16 + r16;
    float bv = bias[col];
#pragma unroll
    for (int r = 0; r < 4; ++r){
      float v = acc[r] * rscale[r] + bv;
      if (doRelu) v = fmaxf(v, 0.f);
      C[(size_t)(m0 + quad * 4 + r) * N + col] = v;
    }
  }
}

extern "C" void kernel_launch(void* const* d_in, const int* in_sizes, int n_in,
                              void* d_out, int out_size, void* d_ws, size_t ws_size,
                              hipStream_t stream){
  const float* x_a = (const float*)d_in[0];
  const float* x_b = (const float*)d_in[1];
  const float* W1b = (const float*)d_in[2];
  const float* b1b = (const float*)d_in[3];
  const float* W1i = (const float*)d_in[4];
  const float* b1i = (const float*)d_in[5];
  const float* W2b = (const float*)d_in[6];
  const float* b2b = (const float*)d_in[7];
  const float* W2i = (const float*)d_in[8];
  const float* b2i = (const float*)d_in[9];
  const int* bs  = (const int*)d_in[10];
  const int* bd  = (const int*)d_in[11];
  const int* isc = (const int*)d_in[12];
  const int* idt = (const int*)d_in[13];

  char* w = (char*)d_ws;
  size_t o = 0;
  auto take = [&](size_t bytes) -> void* {
    void* p = w + o; o = (o + bytes + 255) & ~(size_t)255; return p;
  };
  int* cnts = (int*)take(120000 * sizeof(int));   // c_bs[50k] c_bd[10k] c_is[10k] c_id[50k]
  int* c_bs = cnts, *c_bd = cnts + 50000, *c_is = cnts + 60000, *c_id = cnts + 70000;
  int* curs = (int*)take(60000 * sizeof(int));    // cur_bel[10k] cur_inc[50k]
  int* cur_bel = curs, *cur_inc = curs + 10000;
  int* off_bel = (int*)take((NB + 1) * sizeof(int));
  int* off_inc = (int*)take((NA + 1) * sizeof(int));
  int* csr_bel = (int*)take(NE * sizeof(int));
  int* csr_inc = (int*)take(NE * sizeof(int));
  float* s_ob = (float*)take(NA * sizeof(float));
  float* s_ib = (float*)take(NB * sizeof(float));
  float* s_oi = (float*)take(NB * sizeof(float));
  float* s_ii = (float*)take(NA * sizeof(float));
  u16* pwh = (u16*)take(196608 * sizeof(u16));
  u16* pwl = (u16*)take(196608 * sizeof(u16));
  u16* pwh1b = pwh, *pwh1i = pwh + 65536, *pwh2b = pwh + 131072, *pwh2i = pwh + 163840;
  u16* pwl1b = pwl, *pwl1i = pwl + 65536, *pwl2b = pwl + 131072, *pwl2i = pwl + 163840;
  float* P_b = (float*)take((size_t)NB * FDIM * sizeof(float));
  float* P_a = (float*)take((size_t)NA * FDIM * sizeof(float));
  float* H_b = (float*)take((size_t)NB * FDIM * sizeof(float));
  float* H_a = (float*)take((size_t)NA * FDIM * sizeof(float));
  // total ws ~128 MB

  float* out_a = (float*)d_out;                     // [NA,128]
  float* out_b = (float*)d_out + (size_t)NA * 128;  // [NB,128]

  zero_ints<<<469, 256, 0, stream>>>(cnts, 120000, curs, 60000);
  hist_kernel<<<1172, 256, 0, stream>>>(bs, bd, isc, idt, c_bs, c_bd, c_is, c_id);
  scan_kernel<<<2, 1024, 0, stream>>>(c_bd, c_id, off_bel, off_inc);
  scales_kernel<<<196, 256, 0, stream>>>(c_bs, c_bd, c_is, c_id, s_ob, s_ib, s_oi, s_ii);
  fill_kernel<<<1172, 256, 0, stream>>>(bs, bd, isc, idt, off_bel, off_inc,
                                        cur_bel, cur_inc, csr_bel, csr_inc);
  pack_kernel<<<192, 1024, 0, stream>>>(W1b, W1i, W2b, W2i, pwh, pwl);

  // layer 1
  agg_kernel<<<NB / 4, 256, 0, stream>>>(x_a, s_ob, off_bel, csr_bel, P_b, NB);
  agg_kernel<<<NA / 4, 256, 0, stream>>>(x_b, s_oi, off_inc, csr_inc, P_a, NA);
  gemm_kernel<<<157, 256, 0, stream>>>(P_b, pwh1b, pwl1b, b1b, s_ib, H_b, NB, 256, 1);
  gemm_kernel<<<782, 256, 0, stream>>>(P_a, pwh1i, pwl1i, b1i, s_ii, H_a, NA, 256, 1);
  // layer 2 (same graph: reuse CSR + scales; P buffers reused)
  agg_kernel<<<NB / 4, 256, 0, stream>>>(H_a, s_ob, off_bel, csr_bel, P_b, NB);
  agg_kernel<<<NA / 4, 256, 0, stream>>>(H_b, s_oi, off_inc, csr_inc, P_a, NA);
  gemm_kernel<<<157, 256, 0, stream>>>(P_b, pwh2b, pwl2b, b2b, s_ib, out_b, NB, 128, 0);
  gemm_kernel<<<782, 256, 0, stream>>>(P_a, pwh2i, pwl2i, b2i, s_ii, out_a, NA, 128, 0);
}